// Round 4
// baseline (478.435 us; speedup 1.0000x reference)
//
#include <hip/hip_runtime.h>
#include <math.h>

#define NN 50000
#define NE 800000
#define NP 100000
#define NEG_SLOPE 0.2f

// Sum over each 16-lane DPP row, entirely on the VALU pipe (no LDS/bpermute).
// ror8+ror4+quadperm(xor2)+quadperm(xor1) leaves every lane with the row sum.
__device__ __forceinline__ float row_sum16(float v) {
    int x = __float_as_int(v);
    v += __int_as_float(__builtin_amdgcn_update_dpp(0, x, 0x128, 0xF, 0xF, true)); // row_ror:8
    x = __float_as_int(v);
    v += __int_as_float(__builtin_amdgcn_update_dpp(0, x, 0x124, 0xF, 0xF, true)); // row_ror:4
    x = __float_as_int(v);
    v += __int_as_float(__builtin_amdgcn_update_dpp(0, x, 0x4E, 0xF, 0xF, true));  // quad xor2
    x = __float_as_int(v);
    v += __int_as_float(__builtin_amdgcn_update_dpp(0, x, 0xB1, 0xF, 0xF, true));  // quad xor1
    return v;
}

// ---------------- CSR build (graph identical for both layers: build once) ----------------

__global__ void count_deg(const int* __restrict__ dst, int* __restrict__ cnt) {
    int i = blockIdx.x * blockDim.x + threadIdx.x;
    int st = gridDim.x * blockDim.x;
    for (; i < NE; i += st) atomicAdd(&cnt[dst[i]], 1);
}

__global__ __launch_bounds__(1024) void scan_deg(const int* __restrict__ cnt,
                                                 int* __restrict__ rowptr,
                                                 int* __restrict__ cursor) {
    __shared__ int wsum[16];
    __shared__ int carry;
    __shared__ int total;
    int tid = threadIdx.x;
    int lane = tid & 63, w = tid >> 6;
    if (tid == 0) carry = 0;
    __syncthreads();
    for (int base = 0; base < NN; base += 1024) {
        int idx = base + tid;
        int v = (idx < NN) ? cnt[idx] : 0;
        int x = v;
        #pragma unroll
        for (int mm = 1; mm < 64; mm <<= 1) {
            int y = __shfl_up(x, mm, 64);
            if (lane >= mm) x += y;
        }
        if (lane == 63) wsum[w] = x;
        __syncthreads();
        if (w == 0) {
            int orig = (lane < 16) ? wsum[lane] : 0;
            int t = orig;
            #pragma unroll
            for (int mm = 1; mm < 16; mm <<= 1) {
                int y = __shfl_up(t, mm, 64);
                if (lane >= mm) t += y;
            }
            if (lane < 16) wsum[lane] = t - orig;   // exclusive wave-sum prefix
            if (lane == 15) total = t;
        }
        __syncthreads();
        int excl = carry + wsum[w] + x - v;
        if (idx < NN) { rowptr[idx] = excl; cursor[idx] = excl; }
        __syncthreads();
        if (tid == 0) carry += total;
        __syncthreads();
    }
    if (tid == 0) rowptr[NN] = carry;   // == NE
}

__global__ void scatter_edges(const int* __restrict__ src, const int* __restrict__ dst,
                              int* __restrict__ cursor, int* __restrict__ csrc) {
    int i = blockIdx.x * blockDim.x + threadIdx.x;
    int st = gridDim.x * blockDim.x;
    for (; i < NE; i += st) {
        int p = atomicAdd(&cursor[dst[i]], 1);
        csrc[p] = src[i];
    }
}

// ---------------- out[N,128] = A[N,128] @ W[128,128] ----------------
// Wt chunk index XOR-swizzled by (j>>3)&7: the 8 lanes sharing a bank-start get
// 8 distinct bank-quads -> conflict-free b128 reads (was 8-way at linear 132).
// Staging writes become conflict-free too.

__global__ __launch_bounds__(256) void gemm128(const float* __restrict__ A,
                                               const float* __restrict__ W,
                                               float* __restrict__ out, int nrows) {
    __shared__ float Wt[128 * 132];
    __shared__ float rb[16 * 132];
    int tid = threadIdx.x;
    for (int idx = tid; idx < 128 * 128; idx += 256) {
        int k = idx >> 7, j = idx & 127;
        Wt[j * 132 + ((((k >> 2) ^ ((j >> 3) & 7)) << 2) | (k & 3))] = W[idx];
    }
    __syncthreads();
    int lane = tid & 63, w = tid >> 6;
    int wsw = ((lane >> 3) & 7) << 2;
    const float* w0p = &Wt[lane * 132];
    const float* w1p = &Wt[(64 + lane) * 132];   // (lane+64)>>3 & 7 == lane>>3 & 7: same swizzle
    int ntiles = (nrows + 15) >> 4;
    for (int t = blockIdx.x; t < ntiles; t += gridDim.x) {
        int r0 = t << 4;
        for (int i = tid; i < 512; i += 256) {
            int rr = r0 + (i >> 5);
            float4 v = {0.f, 0.f, 0.f, 0.f};
            if (rr < nrows) v = ((const float4*)A)[(size_t)rr * 32 + (i & 31)];
            *(float4*)&rb[(i >> 5) * 132 + (i & 31) * 4] = v;
        }
        __syncthreads();
        float acc[4][2] = {};
        #pragma unroll 4
        for (int k4 = 0; k4 < 32; ++k4) {
            float4 wv0 = *(const float4*)&w0p[(k4 << 2) ^ wsw];
            float4 wv1 = *(const float4*)&w1p[(k4 << 2) ^ wsw];
            #pragma unroll
            for (int i2 = 0; i2 < 4; ++i2) {
                float4 av = *(const float4*)&rb[(w * 4 + i2) * 132 + (k4 << 2)];  // wave-uniform
                acc[i2][0] = fmaf(av.x, wv0.x, acc[i2][0]);
                acc[i2][0] = fmaf(av.y, wv0.y, acc[i2][0]);
                acc[i2][0] = fmaf(av.z, wv0.z, acc[i2][0]);
                acc[i2][0] = fmaf(av.w, wv0.w, acc[i2][0]);
                acc[i2][1] = fmaf(av.x, wv1.x, acc[i2][1]);
                acc[i2][1] = fmaf(av.y, wv1.y, acc[i2][1]);
                acc[i2][1] = fmaf(av.z, wv1.z, acc[i2][1]);
                acc[i2][1] = fmaf(av.w, wv1.w, acc[i2][1]);
            }
        }
        #pragma unroll
        for (int i2 = 0; i2 < 4; ++i2) {
            int rr = r0 + w * 4 + i2;
            if (rr < nrows) {
                out[(size_t)rr * 128 + lane]      = acc[i2][0];
                out[(size_t)rr * 128 + 64 + lane] = acc[i2][1];
            }
        }
        __syncthreads();
    }
}

// ---------------- fused GATv2 edge phase: one wave per dst node ----------------
// Anchored online softmax (round-3, verified). Score reduce now via DPP row_sum16
// (VALU pipe; each half-wave is 2 whole DPP rows, so divergence never splits one).
// Depth-2 feature prefetch: 2 outstanding 512B gathers per half-wave stream.

__global__ void gat_fused(const float* __restrict__ feat,
                          const int* __restrict__ rowptr,
                          const int* __restrict__ csrc,
                          const float* __restrict__ attn,
                          const float* __restrict__ resid,
                          float* __restrict__ out) {
    int lane = threadIdx.x & 63;
    int wid = (blockIdx.x * blockDim.x + threadIdx.x) >> 6;
    int nw = (gridDim.x * blockDim.x) >> 6;
    int half = lane >> 5;
    int q = lane & 31;
    const float4* feat4 = (const float4*)feat;
    float4 at = ((const float4*)attn)[q];
    for (int d = wid; d < NN; d += nw) {
        int beg = rowptr[d], end = rowptr[d + 1];
        float4 fd = feat4[(size_t)d * 32 + q];
        float m = -INFINITY, s = 0.f;
        float ax = 0.f, ay = 0.f, az = 0.f, aw = 0.f;
        bool first = true;
        int i = beg + half;
        float4 f0 = {0.f, 0.f, 0.f, 0.f}, f1 = {0.f, 0.f, 0.f, 0.f};
        if (i < end)     { int s0 = csrc[i];     f0 = feat4[(size_t)s0 * 32 + q]; }
        if (i + 2 < end) { int s1 = csrc[i + 2]; f1 = feat4[(size_t)s1 * 32 + q]; }
        int s2 = (i + 4 < end) ? csrc[i + 4] : 0;
        while (i < end) {
            float4 f2 = {0.f, 0.f, 0.f, 0.f};
            if (i + 4 < end) f2 = feat4[(size_t)s2 * 32 + q];
            int s3 = (i + 6 < end) ? csrc[i + 6] : 0;
            float ex = f0.x + fd.x; ex = ex > 0.f ? ex : NEG_SLOPE * ex;
            float ey = f0.y + fd.y; ey = ey > 0.f ? ey : NEG_SLOPE * ey;
            float ez = f0.z + fd.z; ez = ez > 0.f ? ez : NEG_SLOPE * ez;
            float ew = f0.w + fd.w; ew = ew > 0.f ? ew : NEG_SLOPE * ew;
            float part = ex * at.x + ey * at.y + ez * at.z + ew * at.w;
            part = row_sum16(part);
            // anchored accumulate: p = exp(part - anchor); first edge sets anchor, p=1
            float p = first ? 1.f : __expf(part - m);
            m = first ? part : m;
            first = false;
            s += p;
            ax = fmaf(f0.x, p, ax);
            ay = fmaf(f0.y, p, ay);
            az = fmaf(f0.z, p, az);
            aw = fmaf(f0.w, p, aw);
            f0 = f1; f1 = f2; s2 = s3; i += 2;
        }
        // merge the two half-wave partials (anchors may differ)
        float mo = __shfl_xor(m, 32, 64);
        float so = __shfl_xor(s, 32, 64);
        float ox = __shfl_xor(ax, 32, 64);
        float oy = __shfl_xor(ay, 32, 64);
        float oz = __shfl_xor(az, 32, 64);
        float ow = __shfl_xor(aw, 32, 64);
        float nm = fmaxf(m, mo);
        float sc0 = (m == nm) ? 1.f : __expf(m - nm);    // exp(-inf)=0: empty half drops out
        float sc1 = (mo == nm) ? 1.f : __expf(mo - nm);
        float S = s * sc0 + so * sc1;
        float inv = S > 0.f ? 1.f / S : 0.f;
        float vx = (ax * sc0 + ox * sc1) * inv;
        float vy = (ay * sc0 + oy * sc1) * inv;
        float vz = (az * sc0 + oz * sc1) * inv;
        float vw = (aw * sc0 + ow * sc1) * inv;
        if (resid) {
            float4 r = ((const float4*)resid)[(size_t)d * 32 + q];
            vx += r.x; vy += r.y; vz += r.z; vw += r.w;
        }
        vx = vx > 0.f ? vx : expm1f(vx);
        vy = vy > 0.f ? vy : expm1f(vy);
        vz = vz > 0.f ? vz : expm1f(vz);
        vw = vw > 0.f ? vw : expm1f(vw);
        if (half == 0) {
            float4 o; o.x = vx; o.y = vy; o.z = vz; o.w = vw;
            ((float4*)out)[(size_t)d * 32 + q] = o;
        }
    }
}

// ---------------- predictor: 32-edge tiles, 6 waves, XOR-swizzled z, work-stealing ----
// Per thread 8 rows x 4 cols; per k4: 4 wv + 8 zv b128 -> 19.5 DS-instr/edge.
// z chunk index XOR rg (T2 recipe): the 4 rg row-groups (stride 8*132 == 0 mod 32
// banks) spread over 4 bank-quads -> conflict-free (round-3's 4-way fixed).
// 6 waves (384 thr) restore LDS-pipe issue pressure (round-3's 4 waves starved it).
// Atomic tile counter removes the 4.07-tiles/wave static-schedule tail.
// LDS: W1t 33.8K + W2t 17.4K + 6 zones 101.4K = 152576 B (1 block/CU).

__global__ __launch_bounds__(384, 1) void predictor(const float* __restrict__ h,
                          const int* __restrict__ ps, const int* __restrict__ pd,
                          const int* __restrict__ ns, const int* __restrict__ nd,
                          const float* __restrict__ Wp1, const float* __restrict__ bp1,
                          const float* __restrict__ Wp2, const float* __restrict__ bp2,
                          const float* __restrict__ Wp3, const float* __restrict__ bp3,
                          int* __restrict__ tilectr, float* __restrict__ out) {
    __shared__ float S[38144];
    int tid = threadIdx.x;
    for (int idx = tid; idx < 128 * 64; idx += 384) {
        int k = idx >> 6, c = idx & 63;
        S[c * 132 + k] = Wp1[idx];
    }
    for (int idx = tid; idx < 64 * 64; idx += 384) {
        int k = idx >> 6, c = idx & 63;
        S[8448 + c * 68 + k] = Wp2[idx];
    }
    __syncthreads();
    int lane = tid & 63;
    int w = tid >> 6;
    int cg = lane & 15, rg = lane >> 4;
    int zsw = rg << 2;
    float* zz = S + 12800 + w * 4224;          // wave-private zone: 32 x 132
    float b1v[4], b2v[4], w3v[4];
    #pragma unroll
    for (int i = 0; i < 4; ++i) {
        b1v[i] = bp1[cg + 16 * i];
        b2v[i] = bp2[cg + 16 * i];
        w3v[i] = Wp3[cg + 16 * i];
    }
    float b3 = bp3[0];
    int ge = lane >> 1, gp = lane & 1;          // gather: local edge, half-row part
    int gsw = ((ge >> 3) & 3) << 2;
    const float4* h4 = (const float4*)h;
    const int NT = (2 * NP) / 32;               // 6250 tiles; NP%32==0 -> no pos/neg straddle
    int T = 0;
    while (true) {
        if (lane == 0) T = atomicAdd(tilectr, 1);
        T = __shfl(T, 0, 64);
        if (T >= NT) break;
        // ---- gather z[32][128] (elementwise product), wave-local, swizzled chunks
        int e = T * 32 + ge;
        int a, b;
        if (e < NP) { a = ps[e]; b = pd[e]; }
        else        { a = ns[e - NP]; b = nd[e - NP]; }
        const float4* pa = h4 + (size_t)a * 32 + gp * 16;
        const float4* pb = h4 + (size_t)b * 32 + gp * 16;
        float* zrow = zz + ge * 132;
        #pragma unroll
        for (int qq = 0; qq < 16; ++qq) {
            float4 va = pa[qq];
            float4 vb = pb[qq];
            float4 vz;
            vz.x = va.x * vb.x; vz.y = va.y * vb.y;
            vz.z = va.z * vb.z; vz.w = va.w * vb.w;
            *(float4*)&zrow[((((gp << 4) | qq) << 2) ^ gsw)] = vz;
        }
        // ---- layer 1: out1[32][64] = z @ W1
        float acc[8][4] = {};
        #pragma unroll 2
        for (int k4 = 0; k4 < 32; ++k4) {
            float4 wv[4];
            #pragma unroll
            for (int i = 0; i < 4; ++i)
                wv[i] = *(const float4*)&S[(cg + 16 * i) * 132 + (k4 << 2)];
            #pragma unroll
            for (int j = 0; j < 8; ++j) {
                float4 zv = *(const float4*)&zz[(rg * 8 + j) * 132 + ((k4 << 2) ^ zsw)];
                #pragma unroll
                for (int i = 0; i < 4; ++i) {
                    acc[j][i] = fmaf(zv.x, wv[i].x, acc[j][i]);
                    acc[j][i] = fmaf(zv.y, wv[i].y, acc[j][i]);
                    acc[j][i] = fmaf(zv.z, wv[i].z, acc[j][i]);
                    acc[j][i] = fmaf(zv.w, wv[i].w, acc[j][i]);
                }
            }
        }
        // relu(+bias) -> overlay (stride 68, same XOR swizzle family)
        #pragma unroll
        for (int j = 0; j < 8; ++j) {
            #pragma unroll
            for (int i = 0; i < 4; ++i) {
                int co = cg + 16 * i;
                zz[(rg * 8 + j) * 68 + ((((co >> 2) ^ rg) << 2) | (co & 3))] =
                    fmaxf(acc[j][i] + b1v[i], 0.f);
            }
        }
        // ---- layer 2: out2[32][64] = relu1 @ W2
        float acc2[8][4] = {};
        #pragma unroll 2
        for (int k4 = 0; k4 < 16; ++k4) {
            float4 wv[4];
            #pragma unroll
            for (int i = 0; i < 4; ++i)
                wv[i] = *(const float4*)&S[8448 + (cg + 16 * i) * 68 + (k4 << 2)];
            #pragma unroll
            for (int j = 0; j < 8; ++j) {
                float4 zv = *(const float4*)&zz[(rg * 8 + j) * 68 + ((k4 << 2) ^ zsw)];
                #pragma unroll
                for (int i = 0; i < 4; ++i) {
                    acc2[j][i] = fmaf(zv.x, wv[i].x, acc2[j][i]);
                    acc2[j][i] = fmaf(zv.y, wv[i].y, acc2[j][i]);
                    acc2[j][i] = fmaf(zv.z, wv[i].z, acc2[j][i]);
                    acc2[j][i] = fmaf(zv.w, wv[i].w, acc2[j][i]);
                }
            }
        }
        // ---- layer 3: relu(+bias) . W3, DPP row-sum over the 16 col-groups
        float v[8];
        #pragma unroll
        for (int j = 0; j < 8; ++j) {
            float sv = 0.f;
            #pragma unroll
            for (int i = 0; i < 4; ++i)
                sv = fmaf(fmaxf(acc2[j][i] + b2v[i], 0.f), w3v[i], sv);
            v[j] = row_sum16(sv);
        }
        if (cg == 0) {
            float4 o0, o1;
            o0.x = v[0] + b3; o0.y = v[1] + b3; o0.z = v[2] + b3; o0.w = v[3] + b3;
            o1.x = v[4] + b3; o1.y = v[5] + b3; o1.z = v[6] + b3; o1.w = v[7] + b3;
            *(float4*)&out[T * 32 + rg * 8]     = o0;
            *(float4*)&out[T * 32 + rg * 8 + 4] = o1;
        }
    }
}

extern "C" void kernel_launch(void* const* d_in, const int* in_sizes, int n_in,
                              void* d_out, int out_size, void* d_ws, size_t ws_size,
                              hipStream_t stream) {
    const float* x       = (const float*)d_in[0];
    const int*   src     = (const int*)d_in[1];
    const int*   dst     = (const int*)d_in[2];
    const int*   pos_src = (const int*)d_in[3];
    const int*   pos_dst = (const int*)d_in[4];
    const int*   neg_src = (const int*)d_in[5];
    const int*   neg_dst = (const int*)d_in[6];
    const float* W0      = (const float*)d_in[7];
    const float* attn0   = (const float*)d_in[8];
    const float* W1      = (const float*)d_in[9];
    const float* attn1   = (const float*)d_in[10];
    const float* Wp1     = (const float*)d_in[11];
    const float* bp1     = (const float*)d_in[12];
    const float* Wp2     = (const float*)d_in[13];
    const float* bp2     = (const float*)d_in[14];
    const float* Wp3     = (const float*)d_in[15];
    const float* bp3     = (const float*)d_in[16];

    float* A = (float*)d_ws;                       // feat buffer
    float* B = A + (size_t)NN * 128;               // layer-1 output (h)
    float* C = B + (size_t)NN * 128;               // layer-0 output / residual
    int* cnt    = (int*)(C + (size_t)NN * 128);    // [NN]
    int* rowptr = cnt + NN;                        // [NN+1]
    int* cursor = rowptr + NN + 1;                 // [NN]
    int* csrc   = cursor + NN;                     // [NE]
    int* tilectr = csrc + NE;                      // [1]
    float* out = (float*)d_out;

    // ---- CSR by dst (built once, reused by both layers)
    hipMemsetAsync(cnt, 0, NN * sizeof(int), stream);
    hipMemsetAsync(tilectr, 0, sizeof(int), stream);
    count_deg<<<3125, 256, 0, stream>>>(dst, cnt);
    scan_deg<<<1, 1024, 0, stream>>>(cnt, rowptr, cursor);
    scatter_edges<<<3125, 256, 0, stream>>>(src, dst, cursor, csrc);

    // ---- layer 0: feat=A, out=C, no residual
    gemm128<<<1024, 256, 0, stream>>>(x, W0, A, NN);
    gat_fused<<<3125, 256, 0, stream>>>(A, rowptr, csrc, attn0, nullptr, C);

    // ---- layer 1: feat=A, out=B, residual=C
    gemm128<<<1024, 256, 0, stream>>>(C, W1, A, NN);
    gat_fused<<<3125, 256, 0, stream>>>(A, rowptr, csrc, attn1, C, B);

    // ---- predictor on h=B: pos -> out[0..P), neg -> out[P..2P)
    predictor<<<256, 384, 0, stream>>>(B, pos_src, pos_dst, neg_src, neg_dst,
                                       Wp1, bp1, Wp2, bp2, Wp3, bp3, tilectr, out);
}

// Round 5
// 451.472 us; speedup vs baseline: 1.0597x; 1.0597x over previous
//
#include <hip/hip_runtime.h>
#include <math.h>

#define NN 50000
#define NE 800000
#define NP 100000
#define NEG_SLOPE 0.2f

// ---------------- CSR build (graph identical for both layers: build once) ----------------

__global__ void count_deg(const int* __restrict__ dst, int* __restrict__ cnt) {
    int i = blockIdx.x * blockDim.x + threadIdx.x;
    int st = gridDim.x * blockDim.x;
    for (; i < NE; i += st) atomicAdd(&cnt[dst[i]], 1);
}

__global__ __launch_bounds__(1024) void scan_deg(const int* __restrict__ cnt,
                                                 int* __restrict__ rowptr,
                                                 int* __restrict__ cursor) {
    __shared__ int wsum[16];
    __shared__ int carry;
    __shared__ int total;
    int tid = threadIdx.x;
    int lane = tid & 63, w = tid >> 6;
    if (tid == 0) carry = 0;
    __syncthreads();
    for (int base = 0; base < NN; base += 1024) {
        int idx = base + tid;
        int v = (idx < NN) ? cnt[idx] : 0;
        int x = v;
        #pragma unroll
        for (int mm = 1; mm < 64; mm <<= 1) {
            int y = __shfl_up(x, mm, 64);
            if (lane >= mm) x += y;
        }
        if (lane == 63) wsum[w] = x;
        __syncthreads();
        if (w == 0) {
            int orig = (lane < 16) ? wsum[lane] : 0;
            int t = orig;
            #pragma unroll
            for (int mm = 1; mm < 16; mm <<= 1) {
                int y = __shfl_up(t, mm, 64);
                if (lane >= mm) t += y;
            }
            if (lane < 16) wsum[lane] = t - orig;   // exclusive wave-sum prefix
            if (lane == 15) total = t;
        }
        __syncthreads();
        int excl = carry + wsum[w] + x - v;
        if (idx < NN) { rowptr[idx] = excl; cursor[idx] = excl; }
        __syncthreads();
        if (tid == 0) carry += total;
        __syncthreads();
    }
    if (tid == 0) rowptr[NN] = carry;   // == NE
}

__global__ void scatter_edges(const int* __restrict__ src, const int* __restrict__ dst,
                              int* __restrict__ cursor, int* __restrict__ csrc) {
    int i = blockIdx.x * blockDim.x + threadIdx.x;
    int st = gridDim.x * blockDim.x;
    for (; i < NE; i += st) {
        int p = atomicAdd(&cursor[dst[i]], 1);
        csrc[p] = src[i];
    }
}

// ---------------- out[N,128] = A[N,128] @ W[128,128], 16-row x 128-col tile ----------------
// (r3 version, best measured) W transposed in LDS (stride 132); per k4: 2 col b128 +
// 4 row-broadcast b128 feed 32 FMAs.

__global__ __launch_bounds__(256) void gemm128(const float* __restrict__ A,
                                               const float* __restrict__ W,
                                               float* __restrict__ out, int nrows) {
    __shared__ float Wt[128 * 132];      // Wt[j*132+k] = W[k*128+j]
    __shared__ float rb[16 * 132];       // row tile, stride 132
    int tid = threadIdx.x;
    for (int idx = tid; idx < 128 * 128; idx += 256) {
        int k = idx >> 7, j = idx & 127;
        Wt[j * 132 + k] = W[idx];
    }
    __syncthreads();
    int lane = tid & 63, w = tid >> 6;
    int ntiles = (nrows + 15) >> 4;
    const float* w0p = &Wt[lane * 132];
    const float* w1p = &Wt[(64 + lane) * 132];
    for (int t = blockIdx.x; t < ntiles; t += gridDim.x) {
        int r0 = t << 4;
        for (int i = tid; i < 512; i += 256) {
            int rr = r0 + (i >> 5);
            float4 v = {0.f, 0.f, 0.f, 0.f};
            if (rr < nrows) v = ((const float4*)A)[(size_t)rr * 32 + (i & 31)];
            *(float4*)&rb[(i >> 5) * 132 + (i & 31) * 4] = v;
        }
        __syncthreads();
        float acc[4][2] = {};
        #pragma unroll 4
        for (int k4 = 0; k4 < 32; ++k4) {
            float4 wv0 = *(const float4*)&w0p[k4 * 4];
            float4 wv1 = *(const float4*)&w1p[k4 * 4];
            #pragma unroll
            for (int i2 = 0; i2 < 4; ++i2) {
                float4 av = *(const float4*)&rb[(w * 4 + i2) * 132 + k4 * 4];  // wave-uniform
                acc[i2][0] = fmaf(av.x, wv0.x, acc[i2][0]);
                acc[i2][0] = fmaf(av.y, wv0.y, acc[i2][0]);
                acc[i2][0] = fmaf(av.z, wv0.z, acc[i2][0]);
                acc[i2][0] = fmaf(av.w, wv0.w, acc[i2][0]);
                acc[i2][1] = fmaf(av.x, wv1.x, acc[i2][1]);
                acc[i2][1] = fmaf(av.y, wv1.y, acc[i2][1]);
                acc[i2][1] = fmaf(av.z, wv1.z, acc[i2][1]);
                acc[i2][1] = fmaf(av.w, wv1.w, acc[i2][1]);
            }
        }
        #pragma unroll
        for (int i2 = 0; i2 < 4; ++i2) {
            int rr = r0 + w * 4 + i2;
            if (rr < nrows) {
                out[(size_t)rr * 128 + lane]      = acc[i2][0];
                out[(size_t)rr * 128 + 64 + lane] = acc[i2][1];
            }
        }
        __syncthreads();
    }
}

// ---------------- fused GATv2 edge phase: one wave per dst node ----------------
// (r3 version, best measured) Anchored online softmax: 1 __expf + 5 FMA per edge.

__global__ void gat_fused(const float* __restrict__ feat,
                          const int* __restrict__ rowptr,
                          const int* __restrict__ csrc,
                          const float* __restrict__ attn,
                          const float* __restrict__ resid,
                          float* __restrict__ out) {
    int lane = threadIdx.x & 63;
    int wid = (blockIdx.x * blockDim.x + threadIdx.x) >> 6;
    int nw = (gridDim.x * blockDim.x) >> 6;
    int half = lane >> 5;
    int q = lane & 31;
    const float4* feat4 = (const float4*)feat;
    float4 at = ((const float4*)attn)[q];
    for (int d = wid; d < NN; d += nw) {
        int beg = rowptr[d], end = rowptr[d + 1];
        float4 fd = feat4[(size_t)d * 32 + q];
        float m = -INFINITY, s = 0.f;
        float ax = 0.f, ay = 0.f, az = 0.f, aw = 0.f;
        bool first = true;
        int i = beg + half;
        int sn = (i < end) ? csrc[i] : 0;
        float4 f = {0.f, 0.f, 0.f, 0.f};
        if (i < end) f = feat4[(size_t)sn * 32 + q];
        int snn = (i + 2 < end) ? csrc[i + 2] : 0;
        while (i < end) {
            float4 fn = {0.f, 0.f, 0.f, 0.f};
            if (i + 2 < end) fn = feat4[(size_t)snn * 32 + q];
            int sn2 = (i + 4 < end) ? csrc[i + 4] : 0;
            float ex = f.x + fd.x; ex = ex > 0.f ? ex : NEG_SLOPE * ex;
            float ey = f.y + fd.y; ey = ey > 0.f ? ey : NEG_SLOPE * ey;
            float ez = f.z + fd.z; ez = ez > 0.f ? ez : NEG_SLOPE * ez;
            float ew = f.w + fd.w; ew = ew > 0.f ? ew : NEG_SLOPE * ew;
            float part = ex * at.x + ey * at.y + ez * at.z + ew * at.w;
            part += __shfl_xor(part, 8, 64);
            part += __shfl_xor(part, 4, 64);
            part += __shfl_xor(part, 2, 64);
            part += __shfl_xor(part, 1, 64);
            // anchored accumulate: p = exp(part - anchor); first edge sets anchor, p=1
            float p = first ? 1.f : __expf(part - m);
            m = first ? part : m;
            first = false;
            s += p;
            ax = fmaf(f.x, p, ax);
            ay = fmaf(f.y, p, ay);
            az = fmaf(f.z, p, az);
            aw = fmaf(f.w, p, aw);
            f = fn; snn = sn2; i += 2;
        }
        // merge the two half-wave partials (anchors may differ)
        float mo = __shfl_xor(m, 32, 64);
        float so = __shfl_xor(s, 32, 64);
        float ox = __shfl_xor(ax, 32, 64);
        float oy = __shfl_xor(ay, 32, 64);
        float oz = __shfl_xor(az, 32, 64);
        float ow = __shfl_xor(aw, 32, 64);
        float nm = fmaxf(m, mo);
        float sc0 = (m == nm) ? 1.f : __expf(m - nm);    // exp(-inf)=0: empty half drops out
        float sc1 = (mo == nm) ? 1.f : __expf(mo - nm);
        float S = s * sc0 + so * sc1;
        float inv = S > 0.f ? 1.f / S : 0.f;
        float vx = (ax * sc0 + ox * sc1) * inv;
        float vy = (ay * sc0 + oy * sc1) * inv;
        float vz = (az * sc0 + oz * sc1) * inv;
        float vw = (aw * sc0 + ow * sc1) * inv;
        if (resid) {
            float4 r = ((const float4*)resid)[(size_t)d * 32 + q];
            vx += r.x; vy += r.y; vz += r.z; vw += r.w;
        }
        vx = vx > 0.f ? vx : expm1f(vx);
        vy = vy > 0.f ? vy : expm1f(vy);
        vz = vz > 0.f ? vz : expm1f(vz);
        vw = vw > 0.f ? vw : expm1f(vw);
        if (half == 0) {
            float4 o; o.x = vx; o.y = vy; o.z = vz; o.w = vw;
            ((float4*)out)[(size_t)d * 32 + q] = o;
        }
    }
}

// ---------------- predictor: r2's proven 16-edge-tile shape, widened to 12 waves ----------
// VALU-issue-bound kernel; the lever is waves/SIMD (r2: 8 waves = 2/SIMD, VALUBusy 52%).
// 768 threads = 12 waves = 3/SIMD at identical per-edge instruction cost.
// Per thread 4 rows x 4 cols; per k4: 4 wv + 4 zv b128 feed 64 FMAs.
// Per-wave private zone (z stride 132, relu1 overlay stride 68), no __syncthreads in loop.
// LDS: W1t 33.8K + W2t 17.4K + 12 zones 101.4K = 152576 B (1 block/CU).

__global__ __launch_bounds__(768, 1) void predictor(const float* __restrict__ h,
                          const int* __restrict__ ps, const int* __restrict__ pd,
                          const int* __restrict__ ns, const int* __restrict__ nd,
                          const float* __restrict__ Wp1, const float* __restrict__ bp1,
                          const float* __restrict__ Wp2, const float* __restrict__ bp2,
                          const float* __restrict__ Wp3, const float* __restrict__ bp3,
                          float* __restrict__ out) {
    __shared__ float S[38144];
    int tid = threadIdx.x;
    for (int idx = tid; idx < 128 * 64; idx += 768) {
        int k = idx >> 6, c = idx & 63;
        S[c * 132 + k] = Wp1[idx];
    }
    for (int idx = tid; idx < 64 * 64; idx += 768) {
        int k = idx >> 6, c = idx & 63;
        S[8448 + c * 68 + k] = Wp2[idx];
    }
    __syncthreads();
    int lane = tid & 63;
    int w = tid >> 6;
    int cg = lane & 15, rg = lane >> 4;
    float* zz = S + 12800 + w * 2112;          // wave-private zone: 16 x 132
    float b1v[4], b2v[4], w3v[4];
    #pragma unroll
    for (int i = 0; i < 4; ++i) {
        b1v[i] = bp1[cg + 16 * i];
        b2v[i] = bp2[cg + 16 * i];
        w3v[i] = Wp3[cg + 16 * i];
    }
    float b3 = bp3[0];
    int gw = blockIdx.x * 12 + w;
    int gnw = gridDim.x * 12;
    int ge = lane >> 2, gp = lane & 3;          // gather: local edge, quarter-row part
    const float4* h4 = (const float4*)h;
    const int NT = (2 * NP) / 16;               // 12500 tiles; NP%16==0 -> no pos/neg straddle
    for (int T = gw; T < NT; T += gnw) {
        // ---- gather z[16][128] (elementwise product), wave-local
        int e = T * 16 + ge;
        int a, b;
        if (e < NP) { a = ps[e]; b = pd[e]; }
        else        { a = ns[e - NP]; b = nd[e - NP]; }
        const float4* pa = h4 + (size_t)a * 32 + gp;
        const float4* pb = h4 + (size_t)b * 32 + gp;
        #pragma unroll
        for (int qq = 0; qq < 8; ++qq) {
            float4 va = pa[qq * 4];
            float4 vb = pb[qq * 4];
            float4 vz;
            vz.x = va.x * vb.x; vz.y = va.y * vb.y;
            vz.z = va.z * vb.z; vz.w = va.w * vb.w;
            *(float4*)&zz[ge * 132 + gp * 4 + qq * 16] = vz;
        }
        // ---- layer 1: out1[16][64] = z @ W1
        float acc[4][4] = {};
        #pragma unroll 4
        for (int k4 = 0; k4 < 32; ++k4) {
            float4 wv[4], zv[4];
            #pragma unroll
            for (int i = 0; i < 4; ++i)
                wv[i] = *(const float4*)&S[(cg + 16 * i) * 132 + k4 * 4];
            #pragma unroll
            for (int j = 0; j < 4; ++j)
                zv[j] = *(const float4*)&zz[(rg * 4 + j) * 132 + k4 * 4];
            #pragma unroll
            for (int j = 0; j < 4; ++j) {
                #pragma unroll
                for (int i = 0; i < 4; ++i) {
                    acc[j][i] = fmaf(zv[j].x, wv[i].x, acc[j][i]);
                    acc[j][i] = fmaf(zv[j].y, wv[i].y, acc[j][i]);
                    acc[j][i] = fmaf(zv[j].z, wv[i].z, acc[j][i]);
                    acc[j][i] = fmaf(zv[j].w, wv[i].w, acc[j][i]);
                }
            }
        }
        // relu(+bias), write layer-1 activations into the overlay (stride 68)
        #pragma unroll
        for (int j = 0; j < 4; ++j) {
            #pragma unroll
            for (int i = 0; i < 4; ++i)
                zz[(rg * 4 + j) * 68 + cg + 16 * i] = fmaxf(acc[j][i] + b1v[i], 0.f);
        }
        // ---- layer 2: out2[16][64] = relu1 @ W2
        float acc2[4][4] = {};
        #pragma unroll 4
        for (int k4 = 0; k4 < 16; ++k4) {
            float4 wv[4], zv[4];
            #pragma unroll
            for (int i = 0; i < 4; ++i)
                wv[i] = *(const float4*)&S[8448 + (cg + 16 * i) * 68 + k4 * 4];
            #pragma unroll
            for (int j = 0; j < 4; ++j)
                zv[j] = *(const float4*)&zz[(rg * 4 + j) * 68 + k4 * 4];
            #pragma unroll
            for (int j = 0; j < 4; ++j) {
                #pragma unroll
                for (int i = 0; i < 4; ++i) {
                    acc2[j][i] = fmaf(zv[j].x, wv[i].x, acc2[j][i]);
                    acc2[j][i] = fmaf(zv[j].y, wv[i].y, acc2[j][i]);
                    acc2[j][i] = fmaf(zv[j].z, wv[i].z, acc2[j][i]);
                    acc2[j][i] = fmaf(zv[j].w, wv[i].w, acc2[j][i]);
                }
            }
        }
        // ---- layer 3: relu(+bias) . W3, reduce across the 16 col-groups
        float v[4];
        #pragma unroll
        for (int j = 0; j < 4; ++j) {
            float sv = 0.f;
            #pragma unroll
            for (int i = 0; i < 4; ++i)
                sv = fmaf(fmaxf(acc2[j][i] + b2v[i], 0.f), w3v[i], sv);
            v[j] = sv;
        }
        #pragma unroll
        for (int mm = 1; mm <= 8; mm <<= 1) {
            #pragma unroll
            for (int j = 0; j < 4; ++j) v[j] += __shfl_xor(v[j], mm, 64);
        }
        if (cg == 0) {
            float4 o;
            o.x = v[0] + b3; o.y = v[1] + b3; o.z = v[2] + b3; o.w = v[3] + b3;
            *(float4*)&out[T * 16 + rg * 4] = o;
        }
    }
}

extern "C" void kernel_launch(void* const* d_in, const int* in_sizes, int n_in,
                              void* d_out, int out_size, void* d_ws, size_t ws_size,
                              hipStream_t stream) {
    const float* x       = (const float*)d_in[0];
    const int*   src     = (const int*)d_in[1];
    const int*   dst     = (const int*)d_in[2];
    const int*   pos_src = (const int*)d_in[3];
    const int*   pos_dst = (const int*)d_in[4];
    const int*   neg_src = (const int*)d_in[5];
    const int*   neg_dst = (const int*)d_in[6];
    const float* W0      = (const float*)d_in[7];
    const float* attn0   = (const float*)d_in[8];
    const float* W1      = (const float*)d_in[9];
    const float* attn1   = (const float*)d_in[10];
    const float* Wp1     = (const float*)d_in[11];
    const float* bp1     = (const float*)d_in[12];
    const float* Wp2     = (const float*)d_in[13];
    const float* bp2     = (const float*)d_in[14];
    const float* Wp3     = (const float*)d_in[15];
    const float* bp3     = (const float*)d_in[16];

    float* A = (float*)d_ws;                       // feat buffer
    float* B = A + (size_t)NN * 128;               // layer-1 output (h)
    float* C = B + (size_t)NN * 128;               // layer-0 output / residual
    int* cnt    = (int*)(C + (size_t)NN * 128);    // [NN]
    int* rowptr = cnt + NN;                        // [NN+1]
    int* cursor = rowptr + NN + 1;                 // [NN]
    int* csrc   = cursor + NN;                     // [NE]
    float* out = (float*)d_out;

    // ---- CSR by dst (built once, reused by both layers)
    hipMemsetAsync(cnt, 0, NN * sizeof(int), stream);
    count_deg<<<3125, 256, 0, stream>>>(dst, cnt);
    scan_deg<<<1, 1024, 0, stream>>>(cnt, rowptr, cursor);
    scatter_edges<<<3125, 256, 0, stream>>>(src, dst, cursor, csrc);

    // ---- layer 0: feat=A, out=C, no residual
    gemm128<<<1024, 256, 0, stream>>>(x, W0, A, NN);
    gat_fused<<<3125, 256, 0, stream>>>(A, rowptr, csrc, attn0, nullptr, C);

    // ---- layer 1: feat=A, out=B, residual=C
    gemm128<<<1024, 256, 0, stream>>>(C, W1, A, NN);
    gat_fused<<<3125, 256, 0, stream>>>(A, rowptr, csrc, attn1, C, B);

    // ---- predictor on h=B: pos -> out[0..P), neg -> out[P..2P)
    predictor<<<256, 768, 0, stream>>>(B, pos_src, pos_dst, neg_src, neg_dst,
                                       Wp1, bp1, Wp2, bp2, Wp3, bp3, out);
}

// Round 6
// 440.330 us; speedup vs baseline: 1.0865x; 1.0253x over previous
//
#include <hip/hip_runtime.h>
#include <math.h>

#define NN 50000
#define NE 800000
#define NP 100000
#define NEG_SLOPE 0.2f

// Sum over each 16-lane DPP row, entirely on the VALU pipe (no LDS/bpermute).
// ror8+ror4+quadperm(xor2)+quadperm(xor1): every lane ends with its row's sum.
// (Validated on-harness in round 4.)
__device__ __forceinline__ float row_sum16(float v) {
    int x = __float_as_int(v);
    v += __int_as_float(__builtin_amdgcn_update_dpp(0, x, 0x128, 0xF, 0xF, true)); // row_ror:8
    x = __float_as_int(v);
    v += __int_as_float(__builtin_amdgcn_update_dpp(0, x, 0x124, 0xF, 0xF, true)); // row_ror:4
    x = __float_as_int(v);
    v += __int_as_float(__builtin_amdgcn_update_dpp(0, x, 0x4E, 0xF, 0xF, true));  // quad xor2
    x = __float_as_int(v);
    v += __int_as_float(__builtin_amdgcn_update_dpp(0, x, 0xB1, 0xF, 0xF, true));  // quad xor1
    return v;
}

// ---------------- CSR build (graph identical for both layers: build once) ----------------

__global__ void count_deg(const int* __restrict__ dst, int* __restrict__ cnt) {
    int i = blockIdx.x * blockDim.x + threadIdx.x;
    int st = gridDim.x * blockDim.x;
    for (; i < NE; i += st) atomicAdd(&cnt[dst[i]], 1);
}

__global__ __launch_bounds__(1024) void scan_deg(const int* __restrict__ cnt,
                                                 int* __restrict__ rowptr,
                                                 int* __restrict__ cursor) {
    __shared__ int wsum[16];
    __shared__ int carry;
    __shared__ int total;
    int tid = threadIdx.x;
    int lane = tid & 63, w = tid >> 6;
    if (tid == 0) carry = 0;
    __syncthreads();
    for (int base = 0; base < NN; base += 1024) {
        int idx = base + tid;
        int v = (idx < NN) ? cnt[idx] : 0;
        int x = v;
        #pragma unroll
        for (int mm = 1; mm < 64; mm <<= 1) {
            int y = __shfl_up(x, mm, 64);
            if (lane >= mm) x += y;
        }
        if (lane == 63) wsum[w] = x;
        __syncthreads();
        if (w == 0) {
            int orig = (lane < 16) ? wsum[lane] : 0;
            int t = orig;
            #pragma unroll
            for (int mm = 1; mm < 16; mm <<= 1) {
                int y = __shfl_up(t, mm, 64);
                if (lane >= mm) t += y;
            }
            if (lane < 16) wsum[lane] = t - orig;   // exclusive wave-sum prefix
            if (lane == 15) total = t;
        }
        __syncthreads();
        int excl = carry + wsum[w] + x - v;
        if (idx < NN) { rowptr[idx] = excl; cursor[idx] = excl; }
        __syncthreads();
        if (tid == 0) carry += total;
        __syncthreads();
    }
    if (tid == 0) rowptr[NN] = carry;   // == NE
}

__global__ void scatter_edges(const int* __restrict__ src, const int* __restrict__ dst,
                              int* __restrict__ cursor, int* __restrict__ csrc) {
    int i = blockIdx.x * blockDim.x + threadIdx.x;
    int st = gridDim.x * blockDim.x;
    for (; i < NE; i += st) {
        int p = atomicAdd(&cursor[dst[i]], 1);
        csrc[p] = src[i];
    }
}

// ---------------- out[N,128] = A[N,128] @ W[128,128], 16-row x 128-col tile ----------------
// (r3 version, best measured) W transposed in LDS (stride 132); per k4: 2 col b128 +
// 4 row-broadcast b128 feed 32 FMAs.

__global__ __launch_bounds__(256) void gemm128(const float* __restrict__ A,
                                               const float* __restrict__ W,
                                               float* __restrict__ out, int nrows) {
    __shared__ float Wt[128 * 132];      // Wt[j*132+k] = W[k*128+j]
    __shared__ float rb[16 * 132];       // row tile, stride 132
    int tid = threadIdx.x;
    for (int idx = tid; idx < 128 * 128; idx += 256) {
        int k = idx >> 7, j = idx & 127;
        Wt[j * 132 + k] = W[idx];
    }
    __syncthreads();
    int lane = tid & 63, w = tid >> 6;
    int ntiles = (nrows + 15) >> 4;
    const float* w0p = &Wt[lane * 132];
    const float* w1p = &Wt[(64 + lane) * 132];
    for (int t = blockIdx.x; t < ntiles; t += gridDim.x) {
        int r0 = t << 4;
        for (int i = tid; i < 512; i += 256) {
            int rr = r0 + (i >> 5);
            float4 v = {0.f, 0.f, 0.f, 0.f};
            if (rr < nrows) v = ((const float4*)A)[(size_t)rr * 32 + (i & 31)];
            *(float4*)&rb[(i >> 5) * 132 + (i & 31) * 4] = v;
        }
        __syncthreads();
        float acc[4][2] = {};
        #pragma unroll 4
        for (int k4 = 0; k4 < 32; ++k4) {
            float4 wv0 = *(const float4*)&w0p[k4 * 4];
            float4 wv1 = *(const float4*)&w1p[k4 * 4];
            #pragma unroll
            for (int i2 = 0; i2 < 4; ++i2) {
                float4 av = *(const float4*)&rb[(w * 4 + i2) * 132 + k4 * 4];  // wave-uniform
                acc[i2][0] = fmaf(av.x, wv0.x, acc[i2][0]);
                acc[i2][0] = fmaf(av.y, wv0.y, acc[i2][0]);
                acc[i2][0] = fmaf(av.z, wv0.z, acc[i2][0]);
                acc[i2][0] = fmaf(av.w, wv0.w, acc[i2][0]);
                acc[i2][1] = fmaf(av.x, wv1.x, acc[i2][1]);
                acc[i2][1] = fmaf(av.y, wv1.y, acc[i2][1]);
                acc[i2][1] = fmaf(av.z, wv1.z, acc[i2][1]);
                acc[i2][1] = fmaf(av.w, wv1.w, acc[i2][1]);
            }
        }
        #pragma unroll
        for (int i2 = 0; i2 < 4; ++i2) {
            int rr = r0 + w * 4 + i2;
            if (rr < nrows) {
                out[(size_t)rr * 128 + lane]      = acc[i2][0];
                out[(size_t)rr * 128 + 64 + lane] = acc[i2][1];
            }
        }
        __syncthreads();
    }
}

// ---------------- fused GATv2 edge phase: one node per 32-lane HALF-wave ----------------
// 32 lanes x float4 = 128 dims; head0 = lanes 0-15, head1 = lanes 16-31 (DPP rows!)
// -> per-head dot via row_sum16 on the VALU pipe (no shfl on the LDS pipe).
// Two independent node streams per wave + prefetch depth 3 = 6 outstanding gathers/wave
// (was 2): attacks the gather-latency bound. No cross-half merge needed.
// Anchored softmax (r3-verified): 1 __expf + 5 FMA steady-state per edge.

__global__ void gat_fused(const float* __restrict__ feat,
                          const int* __restrict__ rowptr,
                          const int* __restrict__ csrc,
                          const float* __restrict__ attn,
                          const float* __restrict__ resid,
                          float* __restrict__ out) {
    int tid = blockIdx.x * blockDim.x + threadIdx.x;
    int hw = tid >> 5;                       // half-wave id = node stream
    int nhw = (gridDim.x * blockDim.x) >> 5;
    int q = threadIdx.x & 31;                // dim quad: dims 4q..4q+3
    const float4* feat4 = (const float4*)feat;
    float4 at = ((const float4*)attn)[q];
    for (int d = hw; d < NN; d += nhw) {
        int beg = rowptr[d], end = rowptr[d + 1];
        float4 fd = feat4[(size_t)d * 32 + q];
        float m = 0.f, s = 0.f;
        float ax = 0.f, ay = 0.f, az = 0.f, aw = 0.f;
        bool first = true;
        int i = beg;
        float4 f0 = {0.f,0.f,0.f,0.f}, f1 = {0.f,0.f,0.f,0.f}, f2 = {0.f,0.f,0.f,0.f};
        if (i     < end) f0 = feat4[(size_t)csrc[i]     * 32 + q];
        if (i + 1 < end) f1 = feat4[(size_t)csrc[i + 1] * 32 + q];
        if (i + 2 < end) f2 = feat4[(size_t)csrc[i + 2] * 32 + q];
        int s3 = (i + 3 < end) ? csrc[i + 3] : 0;
        while (i < end) {
            float4 f3 = {0.f, 0.f, 0.f, 0.f};
            if (i + 3 < end) f3 = feat4[(size_t)s3 * 32 + q];
            int s4 = (i + 4 < end) ? csrc[i + 4] : 0;
            float ex = f0.x + fd.x; ex = ex > 0.f ? ex : NEG_SLOPE * ex;
            float ey = f0.y + fd.y; ey = ey > 0.f ? ey : NEG_SLOPE * ey;
            float ez = f0.z + fd.z; ez = ez > 0.f ? ez : NEG_SLOPE * ez;
            float ew = f0.w + fd.w; ew = ew > 0.f ? ew : NEG_SLOPE * ew;
            float part = ex * at.x + ey * at.y + ez * at.z + ew * at.w;
            part = row_sum16(part);          // per-head sum: each 16-lane group = one head
            // anchored accumulate: p = exp(part - anchor); first edge sets anchor, p = 1
            float p = first ? 1.f : __expf(part - m);
            m = first ? part : m;
            first = false;
            s += p;
            ax = fmaf(f0.x, p, ax);
            ay = fmaf(f0.y, p, ay);
            az = fmaf(f0.z, p, az);
            aw = fmaf(f0.w, p, aw);
            f0 = f1; f1 = f2; f2 = f3; s3 = s4; ++i;
        }
        float inv = s > 0.f ? 1.f / s : 0.f;   // deg==0 -> 0 (matches reference: rst=0)
        float vx = ax * inv;
        float vy = ay * inv;
        float vz = az * inv;
        float vw = aw * inv;
        if (resid) {
            float4 r = ((const float4*)resid)[(size_t)d * 32 + q];
            vx += r.x; vy += r.y; vz += r.z; vw += r.w;
        }
        vx = vx > 0.f ? vx : expm1f(vx);
        vy = vy > 0.f ? vy : expm1f(vy);
        vz = vz > 0.f ? vz : expm1f(vz);
        vw = vw > 0.f ? vw : expm1f(vw);
        float4 o; o.x = vx; o.y = vy; o.z = vz; o.w = vw;
        ((float4*)out)[(size_t)d * 32 + q] = o;
    }
}

// ---------------- predictor: r2's measured-best config (512 thr / 8 waves / 16-edge tiles) ----
// LDS-pipe-bound (r5 lesson: 12 waves regressed, bank conflicts unchanged -> pipe saturated
// at 2 waves/SIMD). Only delta vs r2: final reduce via DPP row_sum16 (VALU) instead of
// 16 shfl_xor (LDS pipe).
// Per thread 4 rows x 4 cols; per k4: 4 wv + 4 zv b128 feed 64 FMAs.
// LDS: W1t 33.8K + W2t 17.4K + 8 zones 67.6K = 118784 B (1 block/CU).

__global__ __launch_bounds__(512, 1) void predictor(const float* __restrict__ h,
                          const int* __restrict__ ps, const int* __restrict__ pd,
                          const int* __restrict__ ns, const int* __restrict__ nd,
                          const float* __restrict__ Wp1, const float* __restrict__ bp1,
                          const float* __restrict__ Wp2, const float* __restrict__ bp2,
                          const float* __restrict__ Wp3, const float* __restrict__ bp3,
                          float* __restrict__ out) {
    __shared__ float S[29696];
    int tid = threadIdx.x;
    for (int idx = tid; idx < 128 * 64; idx += 512) {
        int k = idx >> 6, c = idx & 63;
        S[c * 132 + k] = Wp1[idx];
    }
    for (int idx = tid; idx < 64 * 64; idx += 512) {
        int k = idx >> 6, c = idx & 63;
        S[8448 + c * 68 + k] = Wp2[idx];
    }
    __syncthreads();
    int lane = tid & 63;
    int w = tid >> 6;
    int cg = lane & 15, rg = lane >> 4;
    float* zz = S + 12800 + w * 2112;          // wave-private zone: 16 x 132
    float b1v[4], b2v[4], w3v[4];
    #pragma unroll
    for (int i = 0; i < 4; ++i) {
        b1v[i] = bp1[cg + 16 * i];
        b2v[i] = bp2[cg + 16 * i];
        w3v[i] = Wp3[cg + 16 * i];
    }
    float b3 = bp3[0];
    int gw = blockIdx.x * 8 + w;
    int gnw = gridDim.x * 8;
    int ge = lane >> 2, gp = lane & 3;          // gather: local edge, quarter-row part
    const float4* h4 = (const float4*)h;
    const int NT = (2 * NP) / 16;               // 12500 tiles; NP%16==0 -> no pos/neg straddle
    for (int T = gw; T < NT; T += gnw) {
        // ---- gather z[16][128] (elementwise product), wave-local
        int e = T * 16 + ge;
        int a, b;
        if (e < NP) { a = ps[e]; b = pd[e]; }
        else        { a = ns[e - NP]; b = nd[e - NP]; }
        const float4* pa = h4 + (size_t)a * 32 + gp;
        const float4* pb = h4 + (size_t)b * 32 + gp;
        #pragma unroll
        for (int qq = 0; qq < 8; ++qq) {
            float4 va = pa[qq * 4];
            float4 vb = pb[qq * 4];
            float4 vz;
            vz.x = va.x * vb.x; vz.y = va.y * vb.y;
            vz.z = va.z * vb.z; vz.w = va.w * vb.w;
            *(float4*)&zz[ge * 132 + gp * 4 + qq * 16] = vz;
        }
        // ---- layer 1: out1[16][64] = z @ W1
        float acc[4][4] = {};
        #pragma unroll 4
        for (int k4 = 0; k4 < 32; ++k4) {
            float4 wv[4], zv[4];
            #pragma unroll
            for (int i = 0; i < 4; ++i)
                wv[i] = *(const float4*)&S[(cg + 16 * i) * 132 + k4 * 4];
            #pragma unroll
            for (int j = 0; j < 4; ++j)
                zv[j] = *(const float4*)&zz[(rg * 4 + j) * 132 + k4 * 4];
            #pragma unroll
            for (int j = 0; j < 4; ++j) {
                #pragma unroll
                for (int i = 0; i < 4; ++i) {
                    acc[j][i] = fmaf(zv[j].x, wv[i].x, acc[j][i]);
                    acc[j][i] = fmaf(zv[j].y, wv[i].y, acc[j][i]);
                    acc[j][i] = fmaf(zv[j].z, wv[i].z, acc[j][i]);
                    acc[j][i] = fmaf(zv[j].w, wv[i].w, acc[j][i]);
                }
            }
        }
        // relu(+bias), write layer-1 activations into the overlay (stride 68)
        #pragma unroll
        for (int j = 0; j < 4; ++j) {
            #pragma unroll
            for (int i = 0; i < 4; ++i)
                zz[(rg * 4 + j) * 68 + cg + 16 * i] = fmaxf(acc[j][i] + b1v[i], 0.f);
        }
        // ---- layer 2: out2[16][64] = relu1 @ W2
        float acc2[4][4] = {};
        #pragma unroll 4
        for (int k4 = 0; k4 < 16; ++k4) {
            float4 wv[4], zv[4];
            #pragma unroll
            for (int i = 0; i < 4; ++i)
                wv[i] = *(const float4*)&S[8448 + (cg + 16 * i) * 68 + k4 * 4];
            #pragma unroll
            for (int j = 0; j < 4; ++j)
                zv[j] = *(const float4*)&zz[(rg * 4 + j) * 68 + k4 * 4];
            #pragma unroll
            for (int j = 0; j < 4; ++j) {
                #pragma unroll
                for (int i = 0; i < 4; ++i) {
                    acc2[j][i] = fmaf(zv[j].x, wv[i].x, acc2[j][i]);
                    acc2[j][i] = fmaf(zv[j].y, wv[i].y, acc2[j][i]);
                    acc2[j][i] = fmaf(zv[j].z, wv[i].z, acc2[j][i]);
                    acc2[j][i] = fmaf(zv[j].w, wv[i].w, acc2[j][i]);
                }
            }
        }
        // ---- layer 3: relu(+bias) . W3, DPP row-sum over the 16 col-groups (VALU pipe)
        float v[4];
        #pragma unroll
        for (int j = 0; j < 4; ++j) {
            float sv = 0.f;
            #pragma unroll
            for (int i = 0; i < 4; ++i)
                sv = fmaf(fmaxf(acc2[j][i] + b2v[i], 0.f), w3v[i], sv);
            v[j] = row_sum16(sv);
        }
        if (cg == 0) {
            float4 o;
            o.x = v[0] + b3; o.y = v[1] + b3; o.z = v[2] + b3; o.w = v[3] + b3;
            *(float4*)&out[T * 16 + rg * 4] = o;
        }
    }
}

extern "C" void kernel_launch(void* const* d_in, const int* in_sizes, int n_in,
                              void* d_out, int out_size, void* d_ws, size_t ws_size,
                              hipStream_t stream) {
    const float* x       = (const float*)d_in[0];
    const int*   src     = (const int*)d_in[1];
    const int*   dst     = (const int*)d_in[2];
    const int*   pos_src = (const int*)d_in[3];
    const int*   pos_dst = (const int*)d_in[4];
    const int*   neg_src = (const int*)d_in[5];
    const int*   neg_dst = (const int*)d_in[6];
    const float* W0      = (const float*)d_in[7];
    const float* attn0   = (const float*)d_in[8];
    const float* W1      = (const float*)d_in[9];
    const float* attn1   = (const float*)d_in[10];
    const float* Wp1     = (const float*)d_in[11];
    const float* bp1     = (const float*)d_in[12];
    const float* Wp2     = (const float*)d_in[13];
    const float* bp2     = (const float*)d_in[14];
    const float* Wp3     = (const float*)d_in[15];
    const float* bp3     = (const float*)d_in[16];

    float* A = (float*)d_ws;                       // feat buffer
    float* B = A + (size_t)NN * 128;               // layer-1 output (h)
    float* C = B + (size_t)NN * 128;               // layer-0 output / residual
    int* cnt    = (int*)(C + (size_t)NN * 128);    // [NN]
    int* rowptr = cnt + NN;                        // [NN+1]
    int* cursor = rowptr + NN + 1;                 // [NN]
    int* csrc   = cursor + NN;                     // [NE]
    float* out = (float*)d_out;

    // ---- CSR by dst (built once, reused by both layers)
    hipMemsetAsync(cnt, 0, NN * sizeof(int), stream);
    count_deg<<<3125, 256, 0, stream>>>(dst, cnt);
    scan_deg<<<1, 1024, 0, stream>>>(cnt, rowptr, cursor);
    scatter_edges<<<3125, 256, 0, stream>>>(src, dst, cursor, csrc);

    // ---- layer 0: feat=A, out=C, no residual
    gemm128<<<1024, 256, 0, stream>>>(x, W0, A, NN);
    gat_fused<<<3125, 256, 0, stream>>>(A, rowptr, csrc, attn0, nullptr, C);

    // ---- layer 1: feat=A, out=B, residual=C
    gemm128<<<1024, 256, 0, stream>>>(C, W1, A, NN);
    gat_fused<<<3125, 256, 0, stream>>>(A, rowptr, csrc, attn1, C, B);

    // ---- predictor on h=B: pos -> out[0..P), neg -> out[P..2P)
    predictor<<<256, 512, 0, stream>>>(B, pos_src, pos_dst, neg_src, neg_dst,
                                       Wp1, bp1, Wp2, bp2, Wp3, bp3, out);
}